// Round 5
// baseline (969.826 us; speedup 1.0000x reference)
//
#include <hip/hip_runtime.h>

// ---------------------------------------------------------------------------
// GATv2 x4 + MLP readout.  CSR-by-dst build once per call, then per layer:
//   k_transform: xl = x@Wl+bl, xr = x@Wr+br  (16 nodes/block, float4 acc)
//   k_edge: fused score + online-softmax + aggregate. One wave per NODE,
//     chunk = 16 edges, 8 waves/SIMD, all invariants in LDS (see R4).
// CSR build is write-amp-free two-level bucketing:
//   k_hist  -> deg[] histogram
//   scanA/B/C -> rowptr (exclusive scan of deg)
//   k_bucket: scatter packed (dst16|src16, ea) records into the bucket region
//     rowptr[d & ~63] .. (782 sequential streams -> L2 write-combining)
//   k_csr: one block per bucket; LDS cursors; final scatter stays inside the
//     bucket's ~16 KB CSR segment (L2-resident, no HBM write amplification).
// Readout: f64-atomic mean + 1-block MLP.
// NOTE: packing requires N <= 65536 (here N = 50000).
// ---------------------------------------------------------------------------

__device__ __forceinline__ float readlane_f(float v, int l) {
  return __int_as_float(__builtin_amdgcn_readlane(__float_as_int(v), l));
}
__device__ __forceinline__ int rfl(int v) { return __builtin_amdgcn_readfirstlane(v); }

__device__ __forceinline__ void row_to_lds(const float* g, float* l) {
  __builtin_amdgcn_global_load_lds((const __attribute__((address_space(1))) void*)g,
                                   (__attribute__((address_space(3))) void*)l,
                                   4, 0, 0);
}

__global__ void k_hist(const int* __restrict__ dst, int* __restrict__ deg, int E) {
  int e = blockIdx.x * blockDim.x + threadIdx.x;
  if (e < E) atomicAdd(&deg[dst[e]], 1);
}

// ---- parallel exclusive scan over n ints: A (block sums), B (scan sums), C
__global__ void __launch_bounds__(256) k_scanA(const int* __restrict__ deg,
                                               int* __restrict__ bsum, int n) {
  __shared__ int ws[4];
  int tid = threadIdx.x, lane = tid & 63, wv = tid >> 6;
  int base = blockIdx.x * 1024 + tid;
  int s = 0;
  #pragma unroll
  for (int k = 0; k < 4; k++) {
    int i = base + k * 256;
    if (i < n) s += deg[i];
  }
  #pragma unroll
  for (int o = 32; o > 0; o >>= 1) s += __shfl_xor(s, o, 64);
  if (lane == 0) ws[wv] = s;
  __syncthreads();
  if (tid == 0) bsum[blockIdx.x] = ws[0] + ws[1] + ws[2] + ws[3];
}

__global__ void k_scanB(const int* __restrict__ bsum, int* __restrict__ boffs,
                        int* __restrict__ rowptr, int nb, int n) {
  int lane = threadIdx.x;  // 64 threads, nb <= 64
  int v = (lane < nb) ? bsum[lane] : 0;
  int x = v;
  #pragma unroll
  for (int o = 1; o < 64; o <<= 1) {
    int t = __shfl_up(x, o, 64);
    if (lane >= o) x += t;
  }
  if (lane < nb) boffs[lane] = x - v;
  if (lane == 63) rowptr[n] = x;
}

__global__ void __launch_bounds__(256) k_scanC(const int* __restrict__ deg,
                                               const int* __restrict__ boffs,
                                               int* __restrict__ rowptr, int n) {
  __shared__ int wtot[4];
  int tid = threadIdx.x, lane = tid & 63, wv = tid >> 6;
  int i0 = blockIdx.x * 1024 + tid * 4;
  int4 v = make_int4(0, 0, 0, 0);
  if (i0 + 3 < n) v = *(const int4*)(deg + i0);
  else {
    if (i0 + 0 < n) v.x = deg[i0 + 0];
    if (i0 + 1 < n) v.y = deg[i0 + 1];
    if (i0 + 2 < n) v.z = deg[i0 + 2];
  }
  int s = v.x + v.y + v.z + v.w;
  int x = s;
  #pragma unroll
  for (int o = 1; o < 64; o <<= 1) {
    int t = __shfl_up(x, o, 64);
    if (lane >= o) x += t;
  }
  if (lane == 63) wtot[wv] = x;
  __syncthreads();
  int wexcl = 0;
  for (int k = 0; k < 4; k++) if (k < wv) wexcl += wtot[k];
  int excl = boffs[blockIdx.x] + wexcl + (x - s);
  int4 o4;
  o4.x = excl; o4.y = o4.x + v.x; o4.z = o4.y + v.y; o4.w = o4.z + v.z;
  if (i0 + 3 < n) *(int4*)(rowptr + i0) = o4;
  else {
    if (i0 + 0 < n) rowptr[i0 + 0] = o4.x;
    if (i0 + 1 < n) rowptr[i0 + 1] = o4.y;
    if (i0 + 2 < n) rowptr[i0 + 2] = o4.z;
  }
}

// ---- pass 1: scatter packed records into bucket regions (64 dst per bucket)
__global__ void k_bucket(const int* __restrict__ src, const int* __restrict__ dst,
                         const float* __restrict__ ea_in, const int* __restrict__ rowptr,
                         int* __restrict__ bcur, uint2* __restrict__ tmp, int E) {
  int e = blockIdx.x * blockDim.x + threadIdx.x;
  if (e < E) {
    unsigned d = (unsigned)dst[e];
    int b = d >> 6;
    int pos = rowptr[d & ~63u] + atomicAdd(&bcur[b], 1);
    tmp[pos] = make_uint2((d << 16) | (unsigned)src[e], (unsigned)__float_as_int(ea_in[e]));
  }
}

// ---- pass 2: one block per bucket; LDS cursors; L2-resident final scatter
__global__ void __launch_bounds__(256) k_csr(const int* __restrict__ rowptr,
                                             const uint2* __restrict__ tmp,
                                             int2* __restrict__ pairs, int N) {
  __shared__ int sRP[65];
  __shared__ int cur[64];
  int b = blockIdx.x;
  int n0 = b << 6;
  int tid = threadIdx.x;
  if (tid < 65) {
    int nn = n0 + tid;
    sRP[tid] = rowptr[min(nn, N)];
  }
  if (tid < 64) cur[tid] = 0;
  __syncthreads();
  int lo = sRP[0], hi = sRP[64];
  for (int k = lo + tid; k < hi; k += 256) {
    uint2 rec = tmp[k];
    int local = (int)(rec.x >> 16) - n0;
    int pos = sRP[local] + atomicAdd(&cur[local], 1);
    pairs[pos] = make_int2((int)(rec.x & 0xffffu), (int)rec.y);
  }
}

// xl = x @ Wl + bl ; xr = x @ Wr + br.  16 nodes/block, thread = (node, 4 cols).
template <int DIN>
__global__ void __launch_bounds__(256) k_transform(
    const float* __restrict__ x, const float* __restrict__ Wl, const float* __restrict__ bl,
    const float* __restrict__ Wr, const float* __restrict__ br,
    float* __restrict__ xl, float* __restrict__ xr, int nNodes) {
  __shared__ __align__(16) float sWl[DIN * 64];
  __shared__ __align__(16) float sWr[DIN * 64];
  __shared__ float sx[16][DIN + 1];
  int tid = threadIdx.x;
  for (int i = tid; i < DIN * 64; i += 256) { sWl[i] = Wl[i]; sWr[i] = Wr[i]; }
  int nb = blockIdx.x * 16;
  for (int i = tid; i < 16 * DIN; i += 256) {
    int ln = i / DIN, c = i % DIN;
    int g = nb + ln;
    sx[ln][c] = (g < nNodes) ? x[(size_t)g * DIN + c] : 0.f;
  }
  __syncthreads();
  int node = tid >> 4;          // 0..15
  int t4 = (tid & 15) * 4;      // col group
  float4 accl = *(const float4*)(bl + t4);
  float4 accr = *(const float4*)(br + t4);
  const float* xrow = sx[node];
  #pragma unroll 4
  for (int k = 0; k < DIN; k++) {
    float xv = xrow[k];
    float4 wl = *(const float4*)(sWl + k * 64 + t4);
    float4 wr = *(const float4*)(sWr + k * 64 + t4);
    accl.x = fmaf(xv, wl.x, accl.x); accl.y = fmaf(xv, wl.y, accl.y);
    accl.z = fmaf(xv, wl.z, accl.z); accl.w = fmaf(xv, wl.w, accl.w);
    accr.x = fmaf(xv, wr.x, accr.x); accr.y = fmaf(xv, wr.y, accr.y);
    accr.z = fmaf(xv, wr.z, accr.z); accr.w = fmaf(xv, wr.w, accr.w);
  }
  int g = nb + node;
  if (g < nNodes) {
    *(float4*)(xl + (size_t)g * 64 + t4) = accl;
    *(float4*)(xr + (size_t)g * 64 + t4) = accr;
  }
}

// Fused score + online softmax + aggregate. One wave per node, chunk = 16.
__global__ void __launch_bounds__(256, 8) k_edge(
    const float* __restrict__ xl, const float* __restrict__ xr,
    const int* __restrict__ rowptr, const int* __restrict__ pairs,  // int2 as int*
    const float* __restrict__ We, const float* __restrict__ att,
    const float* __restrict__ bo, float* __restrict__ xout, int nNodes) {
  __shared__ __align__(16) float tile[4][16 * 68];  // 4.35 KB per wave
  __shared__ __align__(16) float sXr[4][64];
  __shared__ __align__(16) float sWe[64];
  __shared__ __align__(16) float sAtt[64];
  int tid = threadIdx.x;
  int lane = tid & 63;
  int wv = rfl(tid >> 6);
  int n = rfl(blockIdx.x * 4 + wv);
  if (tid < 64) { sWe[tid] = We[tid]; sAtt[tid] = att[tid]; }
  bool active = (n < nNodes);
  if (active) sXr[wv][lane] = xr[(size_t)n * 64 + lane];
  __syncthreads();
  if (!active) return;

  float* tw = tile[wv];
  int s0 = rfl(rowptr[n]);
  int s1 = rfl(rowptr[n + 1]);
  int e = lane & 15, q = lane >> 4;
  const float* xq = sXr[wv] + q * 16;
  const float* wq = sWe + q * 16;
  const float* aq = sAtt + q * 16;

  float m = -3.0e38f, d = 0.f, acc0 = 0.f, acc1 = 0.f;

  for (int kb = s0; kb < s1; kb += 16) {
    int cnt = rfl(min(16, s1 - kb));
    // pairs chunk: int2 elements [kb, kb+cnt) read raw by 2*cnt lanes
    int raw = 0;
    if (lane < 2 * cnt) raw = pairs[2 * kb + lane];
    float ea = __int_as_float(__shfl(raw, 2 * e + 1, 64));  // ea of my edge

    // ---- stage xl rows of this chunk into LDS (async DMA, 1 instr/row)
    for (int j = 0; j < cnt; ++j) {
      int s = __builtin_amdgcn_readlane(raw, 2 * j);
      row_to_lds(xl + (size_t)s * 64 + lane, tw + j * 68);
    }
    __builtin_amdgcn_s_waitcnt(0);

    // ---- score: lane (e,q) dots channels [16q,16q+16) of edge e.
    // All non-tile operands come from LDS (broadcast); no VMEM here.
    const float* trow = tw + e * 68 + q * 16;
    float sc = 0.f;
    #pragma unroll 2
    for (int g = 0; g < 4; ++g) {
      float4 tv = *(const float4*)(trow + 4 * g);
      float4 xv = *(const float4*)(xq + 4 * g);
      float4 wvv = *(const float4*)(wq + 4 * g);
      float4 av = *(const float4*)(aq + 4 * g);
      float u;
      u = tv.x + fmaf(ea, wvv.x, xv.x); u = fmaxf(u, 0.2f * u); sc = fmaf(av.x, u, sc);
      u = tv.y + fmaf(ea, wvv.y, xv.y); u = fmaxf(u, 0.2f * u); sc = fmaf(av.y, u, sc);
      u = tv.z + fmaf(ea, wvv.z, xv.z); u = fmaxf(u, 0.2f * u); sc = fmaf(av.z, u, sc);
      u = tv.w + fmaf(ea, wvv.w, xv.w); u = fmaxf(u, 0.2f * u); sc = fmaf(av.w, u, sc);
    }
    sc += __shfl_xor(sc, 16, 64);          // combine the 4 channel quarters
    sc += __shfl_xor(sc, 32, 64);
    sc = (e < cnt) ? sc : -3.0e38f;        // padded edges -> alpha = 0

    // ---- online softmax over 16 edges (quarter-duplicated lanes)
    float mc = sc;
    #pragma unroll
    for (int o = 1; o <= 8; o <<= 1) mc = fmaxf(mc, __shfl_xor(mc, o, 64));
    float newm = fmaxf(m, mc);
    float r = expf(m - newm);              // 0 on first chunk, 1 if max unchanged
    float alpha = expf(sc - newm);
    float ds = alpha;
    #pragma unroll
    for (int o = 1; o <= 8; o <<= 1) ds += __shfl_xor(ds, o, 64);
    d = d * r + ds;
    acc0 *= r; acc1 *= r;
    m = newm;

    // ---- aggregate: lane = channel, fixed 16 iters (alpha=0 masks padding)
    #pragma unroll 4
    for (int j = 0; j < 16; j += 2) {
      acc0 = fmaf(readlane_f(alpha, j),     tw[j * 68 + lane],       acc0);
      acc1 = fmaf(readlane_f(alpha, j + 1), tw[(j + 1) * 68 + lane], acc1);
    }
  }

  float inv = 1.f / (d + 1e-16f);
  float out = (acc0 + acc1) * inv + bo[lane];
  xout[(size_t)n * 64 + lane] = fmaxf(out, 0.f);  // relu after every conv
}

__global__ void k_mean(const float* __restrict__ x, double* __restrict__ meanbuf, int nNodes) {
  __shared__ float sacc[256];
  int lane = threadIdx.x & 63;
  int wv = threadIdx.x >> 6;
  int gw = blockIdx.x * 4 + wv;
  int stride = gridDim.x * 4;
  float acc = 0.f;
  for (int n = gw; n < nNodes; n += stride) acc += x[(size_t)n * 64 + lane];
  sacc[threadIdx.x] = acc;
  __syncthreads();
  if (threadIdx.x < 64) {
    float a = sacc[threadIdx.x] + sacc[threadIdx.x + 64] + sacc[threadIdx.x + 128] + sacc[threadIdx.x + 192];
    atomicAdd(&meanbuf[lane], (double)a);
  }
}

__global__ void k_mlp(const double* __restrict__ meanbuf,
                      const float* __restrict__ Wm1, const float* __restrict__ bm1,
                      const float* __restrict__ Wm2, const float* __restrict__ bm2,
                      const float* __restrict__ Wm3, const float* __restrict__ bm3,
                      float* __restrict__ out, double invN) {
  __shared__ float xm[64];
  __shared__ float h1[32];
  __shared__ float h2[16];
  int t = threadIdx.x;
  xm[t] = (float)(meanbuf[t] * invN);
  __syncthreads();
  if (t < 32) {
    float a = bm1[t];
    for (int c = 0; c < 64; c++) a = fmaf(xm[c], Wm1[c * 32 + t], a);
    h1[t] = fmaxf(a, 0.f);
  }
  __syncthreads();
  if (t < 16) {
    float a = bm2[t];
    for (int c = 0; c < 32; c++) a = fmaf(h1[c], Wm2[c * 16 + t], a);
    h2[t] = fmaxf(a, 0.f);
  }
  __syncthreads();
  if (t == 0) {
    float a = bm3[0];
    for (int c = 0; c < 16; c++) a = fmaf(h2[c], Wm3[c], a);
    out[0] = a;
  }
}

extern "C" void kernel_launch(void* const* d_in, const int* in_sizes, int n_in,
                              void* d_out, int out_size, void* d_ws, size_t ws_size,
                              hipStream_t stream) {
  (void)n_in; (void)out_size; (void)ws_size;
  const int N = in_sizes[0] / 36;   // 50000
  const int E = in_sizes[1];        // 1600000

  const float* feat = (const float*)d_in[0];
  const float* eat  = (const float*)d_in[1];
  const int*   eidx = (const int*)d_in[2];
  const int* src = eidx;
  const int* dst = eidx + E;

  const float* L[4][7];  // Wl, bl, Wr, br, We, att, bo
  for (int l = 0; l < 4; l++)
    for (int j = 0; j < 7; j++) L[l][j] = (const float*)d_in[3 + l * 7 + j];
  const float* Wm1 = (const float*)d_in[31];
  const float* bm1 = (const float*)d_in[32];
  const float* Wm2 = (const float*)d_in[33];
  const float* bm2 = (const float*)d_in[34];
  const float* Wm3 = (const float*)d_in[35];
  const float* bm3 = (const float*)d_in[36];

  const int NB = (N + 63) >> 6;  // buckets of 64 dst nodes (782)

  // workspace layout (512B aligned)
  char* ws = (char*)d_ws;
  size_t off = 0;
  auto alloc = [&](size_t bytes) {
    off = (off + 511) & ~(size_t)511;
    void* p = ws + off;
    off += bytes;
    return p;
  };
  int*    deg     = (int*)alloc((size_t)N * 4);
  int*    bcur    = (int*)alloc((size_t)NB * 4);
  double* meanbuf = (double*)alloc(64 * 8);
  size_t zero_bytes = off;  // deg + bcur + meanbuf
  int*    rowptr  = (int*)alloc((size_t)(N + 1) * 4);
  int*    bsum    = (int*)alloc(64 * 4);
  int*    boffs   = (int*)alloc(64 * 4);
  int2*   pairs   = (int2*)alloc((size_t)E * 8);
  float*  xA      = (float*)alloc((size_t)N * 64 * 4);  // xl
  float*  xB      = (float*)alloc((size_t)N * 64 * 4);  // xr
  float*  xC      = (float*)alloc((size_t)N * 64 * 4);  // layer out / next in
  uint2*  tmp     = (uint2*)xC;  // aliases xC: dead until k_edge layer 1 writes it
                                 // (E*8 = 12.8MB == N*64*4, exact fit)

  hipMemsetAsync(d_ws, 0, zero_bytes, stream);

  int egrid = (E + 255) / 256;
  int tgrid = (N + 15) / 16;  // k_transform: 16 nodes per 256-thr block
  int ngrid = (N + 3) / 4;    // k_edge: 4 nodes (waves) per 256-thr block
  int nb = (N + 1023) / 1024; // scan blocks (49 <= 64)

  k_hist<<<egrid, 256, 0, stream>>>(dst, deg, E);
  k_scanA<<<nb, 256, 0, stream>>>(deg, bsum, N);
  k_scanB<<<1, 64, 0, stream>>>(bsum, boffs, rowptr, nb, N);
  k_scanC<<<nb, 256, 0, stream>>>(deg, boffs, rowptr, N);
  k_bucket<<<egrid, 256, 0, stream>>>(src, dst, eat, rowptr, bcur, tmp, E);
  k_csr<<<NB, 256, 0, stream>>>(rowptr, tmp, pairs, N);

  for (int l = 0; l < 4; l++) {
    if (l == 0)
      k_transform<36><<<tgrid, 256, 0, stream>>>(feat, L[0][0], L[0][1], L[0][2], L[0][3], xA, xB, N);
    else
      k_transform<64><<<tgrid, 256, 0, stream>>>(xC, L[l][0], L[l][1], L[l][2], L[l][3], xA, xB, N);
    k_edge<<<ngrid, 256, 0, stream>>>(xA, xB, rowptr, (const int*)pairs,
                                      L[l][4], L[l][5], L[l][6], xC, N);
  }

  k_mean<<<256, 256, 0, stream>>>(xC, meanbuf, N);
  k_mlp<<<1, 64, 0, stream>>>(meanbuf, Wm1, bm1, Wm2, bm2, Wm3, bm3, (float*)d_out, 1.0 / (double)N);
}

// Round 6
// 615.785 us; speedup vs baseline: 1.5749x; 1.5749x over previous
//
#include <hip/hip_runtime.h>

// ---------------------------------------------------------------------------
// GATv2 x4 + MLP readout.  CSR-by-dst build once per call, then per layer:
//   k_transform: xl = x@Wl+bl, xr = x@Wr+br  (16 nodes/block, float4 acc)
//   k_edge: fused score + online-softmax + aggregate. One wave per NODE,
//     chunk = 16 edges, 8 waves/SIMD, all invariants in LDS (see R4).
// CSR build (write-amp-free AND atomic-contention-free):
//   k_hist -> deg[]; scanA/B/C -> rowptr.
//   k_scatter: per 256-thr block, 4096 edges -> LDS histogram over 196
//     buckets (256 dst/bucket) -> ONE global atomic per touched bucket
//     (bcur padded 1 counter/64B line; ~77k atomics total, not 1.6M) ->
//     scatter packed (dst16|src16, ea) to the block's reserved contiguous
//     sub-ranges (~21 records/bucket -> ~1.4x write amp, not 8x).
//   k_csr: one block per bucket; per-node LDS cursors; final scatter stays
//     inside the bucket's ~64 KB CSR segment (L2-resident full-line writes).
// Readout: f64-atomic mean + 1-block MLP.
// NOTE: packing requires N <= 65536 (here N = 50000).
// R5 lesson: 1.6M device atomics on 782 packed counters (49 lines) serialized
// at ~11ns/line-op = 377us. Atomics must spread over many lines or go to LDS.
// ---------------------------------------------------------------------------

__device__ __forceinline__ float readlane_f(float v, int l) {
  return __int_as_float(__builtin_amdgcn_readlane(__float_as_int(v), l));
}
__device__ __forceinline__ int rfl(int v) { return __builtin_amdgcn_readfirstlane(v); }

__device__ __forceinline__ void row_to_lds(const float* g, float* l) {
  __builtin_amdgcn_global_load_lds((const __attribute__((address_space(1))) void*)g,
                                   (__attribute__((address_space(3))) void*)l,
                                   4, 0, 0);
}

__global__ void k_hist(const int* __restrict__ dst, int* __restrict__ deg, int E) {
  int e = blockIdx.x * blockDim.x + threadIdx.x;
  if (e < E) atomicAdd(&deg[dst[e]], 1);
}

// ---- parallel exclusive scan over n ints: A (block sums), B (scan sums), C
__global__ void __launch_bounds__(256) k_scanA(const int* __restrict__ deg,
                                               int* __restrict__ bsum, int n) {
  __shared__ int ws[4];
  int tid = threadIdx.x, lane = tid & 63, wv = tid >> 6;
  int base = blockIdx.x * 1024 + tid;
  int s = 0;
  #pragma unroll
  for (int k = 0; k < 4; k++) {
    int i = base + k * 256;
    if (i < n) s += deg[i];
  }
  #pragma unroll
  for (int o = 32; o > 0; o >>= 1) s += __shfl_xor(s, o, 64);
  if (lane == 0) ws[wv] = s;
  __syncthreads();
  if (tid == 0) bsum[blockIdx.x] = ws[0] + ws[1] + ws[2] + ws[3];
}

__global__ void k_scanB(const int* __restrict__ bsum, int* __restrict__ boffs,
                        int* __restrict__ rowptr, int nb, int n) {
  int lane = threadIdx.x;  // 64 threads, nb <= 64
  int v = (lane < nb) ? bsum[lane] : 0;
  int x = v;
  #pragma unroll
  for (int o = 1; o < 64; o <<= 1) {
    int t = __shfl_up(x, o, 64);
    if (lane >= o) x += t;
  }
  if (lane < nb) boffs[lane] = x - v;
  if (lane == 63) rowptr[n] = x;
}

__global__ void __launch_bounds__(256) k_scanC(const int* __restrict__ deg,
                                               const int* __restrict__ boffs,
                                               int* __restrict__ rowptr, int n) {
  __shared__ int wtot[4];
  int tid = threadIdx.x, lane = tid & 63, wv = tid >> 6;
  int i0 = blockIdx.x * 1024 + tid * 4;
  int4 v = make_int4(0, 0, 0, 0);
  if (i0 + 3 < n) v = *(const int4*)(deg + i0);
  else {
    if (i0 + 0 < n) v.x = deg[i0 + 0];
    if (i0 + 1 < n) v.y = deg[i0 + 1];
    if (i0 + 2 < n) v.z = deg[i0 + 2];
  }
  int s = v.x + v.y + v.z + v.w;
  int x = s;
  #pragma unroll
  for (int o = 1; o < 64; o <<= 1) {
    int t = __shfl_up(x, o, 64);
    if (lane >= o) x += t;
  }
  if (lane == 63) wtot[wv] = x;
  __syncthreads();
  int wexcl = 0;
  for (int k = 0; k < 4; k++) if (k < wv) wexcl += wtot[k];
  int excl = boffs[blockIdx.x] + wexcl + (x - s);
  int4 o4;
  o4.x = excl; o4.y = o4.x + v.x; o4.z = o4.y + v.y; o4.w = o4.z + v.z;
  if (i0 + 3 < n) *(int4*)(rowptr + i0) = o4;
  else {
    if (i0 + 0 < n) rowptr[i0 + 0] = o4.x;
    if (i0 + 1 < n) rowptr[i0 + 1] = o4.y;
    if (i0 + 2 < n) rowptr[i0 + 2] = o4.z;
  }
}

// ---- pass 1: block-binned scatter into bucket regions (256 dst per bucket)
// NBK buckets; bcur padded to 16 ints (one 64B line) per counter.
#define NBK_MAX 256
__global__ void __launch_bounds__(256) k_scatter(
    const int* __restrict__ src, const int* __restrict__ dst,
    const float* __restrict__ ea_in, const int* __restrict__ rowptr,
    int* __restrict__ bcur, uint2* __restrict__ tmp, int E, int nbk) {
  __shared__ int cnt[NBK_MAX];
  __shared__ int cur[NBK_MAX];
  __shared__ int gbase[NBK_MAX];
  __shared__ int sbase[NBK_MAX];
  int tid = threadIdx.x;
  if (tid < nbk) {
    cnt[tid] = 0;
    cur[tid] = 0;
    sbase[tid] = rowptr[tid << 8];
  }
  __syncthreads();
  int base = blockIdx.x * 4096 + tid;
  uint2 rec[16];
  #pragma unroll
  for (int k = 0; k < 16; k++) {
    int e = base + k * 256;
    if (e < E) {
      unsigned d = (unsigned)dst[e];
      rec[k] = make_uint2((d << 16) | (unsigned)src[e],
                          (unsigned)__float_as_int(ea_in[e]));
      atomicAdd(&cnt[d >> 8], 1);
    } else {
      rec[k] = make_uint2(0u, 0u);
    }
  }
  __syncthreads();
  if (tid < nbk) {
    int c = cnt[tid];
    gbase[tid] = (c > 0) ? atomicAdd(&bcur[tid * 16], c) : 0;
  }
  __syncthreads();
  #pragma unroll
  for (int k = 0; k < 16; k++) {
    int e = base + k * 256;
    if (e < E) {
      int b = (int)(rec[k].x >> 24);
      int slot = atomicAdd(&cur[b], 1);
      tmp[sbase[b] + gbase[b] + slot] = rec[k];
    }
  }
}

// ---- pass 2: one block per bucket; LDS cursors; L2-resident final scatter
__global__ void __launch_bounds__(256) k_csr(const int* __restrict__ rowptr,
                                             const uint2* __restrict__ tmp,
                                             int2* __restrict__ pairs, int N) {
  __shared__ int sRP[257];
  __shared__ int cur[256];
  int b = blockIdx.x;
  int n0 = b << 8;
  int tid = threadIdx.x;
  sRP[tid] = rowptr[min(n0 + tid, N)];
  if (tid == 0) sRP[256] = rowptr[min(n0 + 256, N)];
  cur[tid] = 0;
  __syncthreads();
  int lo = sRP[0], hi = sRP[256];
  for (int k = lo + tid; k < hi; k += 256) {
    uint2 rec = tmp[k];
    int local = (int)(rec.x >> 16) - n0;
    int pos = sRP[local] + atomicAdd(&cur[local], 1);
    pairs[pos] = make_int2((int)(rec.x & 0xffffu), (int)rec.y);
  }
}

// xl = x @ Wl + bl ; xr = x @ Wr + br.  16 nodes/block, thread = (node, 4 cols).
template <int DIN>
__global__ void __launch_bounds__(256) k_transform(
    const float* __restrict__ x, const float* __restrict__ Wl, const float* __restrict__ bl,
    const float* __restrict__ Wr, const float* __restrict__ br,
    float* __restrict__ xl, float* __restrict__ xr, int nNodes) {
  __shared__ __align__(16) float sWl[DIN * 64];
  __shared__ __align__(16) float sWr[DIN * 64];
  __shared__ float sx[16][DIN + 1];
  int tid = threadIdx.x;
  for (int i = tid; i < DIN * 64; i += 256) { sWl[i] = Wl[i]; sWr[i] = Wr[i]; }
  int nb = blockIdx.x * 16;
  for (int i = tid; i < 16 * DIN; i += 256) {
    int ln = i / DIN, c = i % DIN;
    int g = nb + ln;
    sx[ln][c] = (g < nNodes) ? x[(size_t)g * DIN + c] : 0.f;
  }
  __syncthreads();
  int node = tid >> 4;          // 0..15
  int t4 = (tid & 15) * 4;      // col group
  float4 accl = *(const float4*)(bl + t4);
  float4 accr = *(const float4*)(br + t4);
  const float* xrow = sx[node];
  #pragma unroll 4
  for (int k = 0; k < DIN; k++) {
    float xv = xrow[k];
    float4 wl = *(const float4*)(sWl + k * 64 + t4);
    float4 wr = *(const float4*)(sWr + k * 64 + t4);
    accl.x = fmaf(xv, wl.x, accl.x); accl.y = fmaf(xv, wl.y, accl.y);
    accl.z = fmaf(xv, wl.z, accl.z); accl.w = fmaf(xv, wl.w, accl.w);
    accr.x = fmaf(xv, wr.x, accr.x); accr.y = fmaf(xv, wr.y, accr.y);
    accr.z = fmaf(xv, wr.z, accr.z); accr.w = fmaf(xv, wr.w, accr.w);
  }
  int g = nb + node;
  if (g < nNodes) {
    *(float4*)(xl + (size_t)g * 64 + t4) = accl;
    *(float4*)(xr + (size_t)g * 64 + t4) = accr;
  }
}

// Fused score + online softmax + aggregate. One wave per node, chunk = 16.
__global__ void __launch_bounds__(256, 8) k_edge(
    const float* __restrict__ xl, const float* __restrict__ xr,
    const int* __restrict__ rowptr, const int* __restrict__ pairs,  // int2 as int*
    const float* __restrict__ We, const float* __restrict__ att,
    const float* __restrict__ bo, float* __restrict__ xout, int nNodes) {
  __shared__ __align__(16) float tile[4][16 * 68];  // 4.35 KB per wave
  __shared__ __align__(16) float sXr[4][64];
  __shared__ __align__(16) float sWe[64];
  __shared__ __align__(16) float sAtt[64];
  int tid = threadIdx.x;
  int lane = tid & 63;
  int wv = rfl(tid >> 6);
  int n = rfl(blockIdx.x * 4 + wv);
  if (tid < 64) { sWe[tid] = We[tid]; sAtt[tid] = att[tid]; }
  bool active = (n < nNodes);
  if (active) sXr[wv][lane] = xr[(size_t)n * 64 + lane];
  __syncthreads();
  if (!active) return;

  float* tw = tile[wv];
  int s0 = rfl(rowptr[n]);
  int s1 = rfl(rowptr[n + 1]);
  int e = lane & 15, q = lane >> 4;
  const float* xq = sXr[wv] + q * 16;
  const float* wq = sWe + q * 16;
  const float* aq = sAtt + q * 16;

  float m = -3.0e38f, d = 0.f, acc0 = 0.f, acc1 = 0.f;

  for (int kb = s0; kb < s1; kb += 16) {
    int cnt = rfl(min(16, s1 - kb));
    // pairs chunk: int2 elements [kb, kb+cnt) read raw by 2*cnt lanes
    int raw = 0;
    if (lane < 2 * cnt) raw = pairs[2 * kb + lane];
    float ea = __int_as_float(__shfl(raw, 2 * e + 1, 64));  // ea of my edge

    // ---- stage xl rows of this chunk into LDS (async DMA, 1 instr/row)
    for (int j = 0; j < cnt; ++j) {
      int s = __builtin_amdgcn_readlane(raw, 2 * j);
      row_to_lds(xl + (size_t)s * 64 + lane, tw + j * 68);
    }
    __builtin_amdgcn_s_waitcnt(0);

    // ---- score: lane (e,q) dots channels [16q,16q+16) of edge e.
    // All non-tile operands come from LDS (broadcast); no VMEM here.
    const float* trow = tw + e * 68 + q * 16;
    float sc = 0.f;
    #pragma unroll 2
    for (int g = 0; g < 4; ++g) {
      float4 tv = *(const float4*)(trow + 4 * g);
      float4 xv = *(const float4*)(xq + 4 * g);
      float4 wvv = *(const float4*)(wq + 4 * g);
      float4 av = *(const float4*)(aq + 4 * g);
      float u;
      u = tv.x + fmaf(ea, wvv.x, xv.x); u = fmaxf(u, 0.2f * u); sc = fmaf(av.x, u, sc);
      u = tv.y + fmaf(ea, wvv.y, xv.y); u = fmaxf(u, 0.2f * u); sc = fmaf(av.y, u, sc);
      u = tv.z + fmaf(ea, wvv.z, xv.z); u = fmaxf(u, 0.2f * u); sc = fmaf(av.z, u, sc);
      u = tv.w + fmaf(ea, wvv.w, xv.w); u = fmaxf(u, 0.2f * u); sc = fmaf(av.w, u, sc);
    }
    sc += __shfl_xor(sc, 16, 64);          // combine the 4 channel quarters
    sc += __shfl_xor(sc, 32, 64);
    sc = (e < cnt) ? sc : -3.0e38f;        // padded edges -> alpha = 0

    // ---- online softmax over 16 edges (quarter-duplicated lanes)
    float mc = sc;
    #pragma unroll
    for (int o = 1; o <= 8; o <<= 1) mc = fmaxf(mc, __shfl_xor(mc, o, 64));
    float newm = fmaxf(m, mc);
    float r = expf(m - newm);              // 0 on first chunk, 1 if max unchanged
    float alpha = expf(sc - newm);
    float ds = alpha;
    #pragma unroll
    for (int o = 1; o <= 8; o <<= 1) ds += __shfl_xor(ds, o, 64);
    d = d * r + ds;
    acc0 *= r; acc1 *= r;
    m = newm;

    // ---- aggregate: lane = channel, fixed 16 iters (alpha=0 masks padding)
    #pragma unroll 4
    for (int j = 0; j < 16; j += 2) {
      acc0 = fmaf(readlane_f(alpha, j),     tw[j * 68 + lane],       acc0);
      acc1 = fmaf(readlane_f(alpha, j + 1), tw[(j + 1) * 68 + lane], acc1);
    }
  }

  float inv = 1.f / (d + 1e-16f);
  float out = (acc0 + acc1) * inv + bo[lane];
  xout[(size_t)n * 64 + lane] = fmaxf(out, 0.f);  // relu after every conv
}

__global__ void k_mean(const float* __restrict__ x, double* __restrict__ meanbuf, int nNodes) {
  __shared__ float sacc[256];
  int lane = threadIdx.x & 63;
  int wv = threadIdx.x >> 6;
  int gw = blockIdx.x * 4 + wv;
  int stride = gridDim.x * 4;
  float acc = 0.f;
  for (int n = gw; n < nNodes; n += stride) acc += x[(size_t)n * 64 + lane];
  sacc[threadIdx.x] = acc;
  __syncthreads();
  if (threadIdx.x < 64) {
    float a = sacc[threadIdx.x] + sacc[threadIdx.x + 64] + sacc[threadIdx.x + 128] + sacc[threadIdx.x + 192];
    atomicAdd(&meanbuf[lane], (double)a);
  }
}

__global__ void k_mlp(const double* __restrict__ meanbuf,
                      const float* __restrict__ Wm1, const float* __restrict__ bm1,
                      const float* __restrict__ Wm2, const float* __restrict__ bm2,
                      const float* __restrict__ Wm3, const float* __restrict__ bm3,
                      float* __restrict__ out, double invN) {
  __shared__ float xm[64];
  __shared__ float h1[32];
  __shared__ float h2[16];
  int t = threadIdx.x;
  xm[t] = (float)(meanbuf[t] * invN);
  __syncthreads();
  if (t < 32) {
    float a = bm1[t];
    for (int c = 0; c < 64; c++) a = fmaf(xm[c], Wm1[c * 32 + t], a);
    h1[t] = fmaxf(a, 0.f);
  }
  __syncthreads();
  if (t < 16) {
    float a = bm2[t];
    for (int c = 0; c < 32; c++) a = fmaf(h1[c], Wm2[c * 16 + t], a);
    h2[t] = fmaxf(a, 0.f);
  }
  __syncthreads();
  if (t == 0) {
    float a = bm3[0];
    for (int c = 0; c < 16; c++) a = fmaf(h2[c], Wm3[c], a);
    out[0] = a;
  }
}

extern "C" void kernel_launch(void* const* d_in, const int* in_sizes, int n_in,
                              void* d_out, int out_size, void* d_ws, size_t ws_size,
                              hipStream_t stream) {
  (void)n_in; (void)out_size; (void)ws_size;
  const int N = in_sizes[0] / 36;   // 50000
  const int E = in_sizes[1];        // 1600000

  const float* feat = (const float*)d_in[0];
  const float* eat  = (const float*)d_in[1];
  const int*   eidx = (const int*)d_in[2];
  const int* src = eidx;
  const int* dst = eidx + E;

  const float* L[4][7];  // Wl, bl, Wr, br, We, att, bo
  for (int l = 0; l < 4; l++)
    for (int j = 0; j < 7; j++) L[l][j] = (const float*)d_in[3 + l * 7 + j];
  const float* Wm1 = (const float*)d_in[31];
  const float* bm1 = (const float*)d_in[32];
  const float* Wm2 = (const float*)d_in[33];
  const float* bm2 = (const float*)d_in[34];
  const float* Wm3 = (const float*)d_in[35];
  const float* bm3 = (const float*)d_in[36];

  const int NBK = (N + 255) >> 8;  // buckets of 256 dst nodes (196)

  // workspace layout (512B aligned)
  char* ws = (char*)d_ws;
  size_t off = 0;
  auto alloc = [&](size_t bytes) {
    off = (off + 511) & ~(size_t)511;
    void* p = ws + off;
    off += bytes;
    return p;
  };
  int*    deg     = (int*)alloc((size_t)N * 4);
  int*    bcur    = (int*)alloc((size_t)NBK * 16 * 4);  // 1 counter per 64B line
  double* meanbuf = (double*)alloc(64 * 8);
  size_t zero_bytes = off;  // deg + bcur + meanbuf
  int*    rowptr  = (int*)alloc((size_t)(N + 1) * 4);
  int*    bsum    = (int*)alloc(64 * 4);
  int*    boffs   = (int*)alloc(64 * 4);
  int2*   pairs   = (int2*)alloc((size_t)E * 8);
  float*  xA      = (float*)alloc((size_t)N * 64 * 4);  // xl
  float*  xB      = (float*)alloc((size_t)N * 64 * 4);  // xr
  float*  xC      = (float*)alloc((size_t)N * 64 * 4);  // layer out / next in
  uint2*  tmp     = (uint2*)xC;  // aliases xC: dead until k_edge layer 1 writes it
                                 // (E*8 = 12.8MB == N*64*4, exact fit)

  hipMemsetAsync(d_ws, 0, zero_bytes, stream);

  int egrid = (E + 255) / 256;
  int sgrid = (E + 4095) / 4096; // k_scatter: 4096 edges per 256-thr block
  int tgrid = (N + 15) / 16;  // k_transform: 16 nodes per 256-thr block
  int ngrid = (N + 3) / 4;    // k_edge: 4 nodes (waves) per 256-thr block
  int nb = (N + 1023) / 1024; // scan blocks (49 <= 64)

  k_hist<<<egrid, 256, 0, stream>>>(dst, deg, E);
  k_scanA<<<nb, 256, 0, stream>>>(deg, bsum, N);
  k_scanB<<<1, 64, 0, stream>>>(bsum, boffs, rowptr, nb, N);
  k_scanC<<<nb, 256, 0, stream>>>(deg, boffs, rowptr, N);
  k_scatter<<<sgrid, 256, 0, stream>>>(src, dst, eat, rowptr, bcur, tmp, E, NBK);
  k_csr<<<NBK, 256, 0, stream>>>(rowptr, tmp, pairs, N);

  for (int l = 0; l < 4; l++) {
    if (l == 0)
      k_transform<36><<<tgrid, 256, 0, stream>>>(feat, L[0][0], L[0][1], L[0][2], L[0][3], xA, xB, N);
    else
      k_transform<64><<<tgrid, 256, 0, stream>>>(xC, L[l][0], L[l][1], L[l][2], L[l][3], xA, xB, N);
    k_edge<<<ngrid, 256, 0, stream>>>(xA, xB, rowptr, (const int*)pairs,
                                      L[l][4], L[l][5], L[l][6], xC, N);
  }

  k_mean<<<256, 256, 0, stream>>>(xC, meanbuf, N);
  k_mlp<<<1, 64, 0, stream>>>(meanbuf, Wm1, bm1, Wm2, bm2, Wm3, bm3, (float*)d_out, 1.0 / (double)N);
}